// Round 2
// baseline (257.566 us; speedup 1.0000x reference)
//
#include <hip/hip_runtime.h>
#include <math.h>

#define TV 3200          // T*V = 128*25
#define NTV 204800       // N*T*V
#define NQ 51200         // NTV/4 float4 sites
#define NB 400           // blocks of 128 covering NQ exactly
constexpr float EPSF = 1e-5f;

typedef float f4 __attribute__((ext_vector_type(4)));   // native vec for nontemporal builtins

// fast tanh: 1 - 2/(e^{2x}+1); exact saturation at +/-inf, ~1e-7 abs err for |x|<5
__device__ inline float fast_tanh(float x){
  float e = __expf(2.f*x);
  return 1.f - 2.f/(e + 1.f);
}

// ---- two-stage reduction helper for 128-thread (2-wave) blocks ----
template<int NS>
__device__ inline void write_partials(float (&vals)[NS], float* __restrict__ out, float* lds){
  int lane = threadIdx.x & 63;
  int wid  = threadIdx.x >> 6;    // 0..1
  #pragma unroll
  for (int s = 0; s < NS; ++s){
    float v = vals[s];
    #pragma unroll
    for (int o = 32; o > 0; o >>= 1) v += __shfl_down(v, o);
    if (lane == 0) lds[s*2 + wid] = v;
  }
  __syncthreads();
  if ((int)threadIdx.x < NS){
    out[threadIdx.x*NB + blockIdx.x] = lds[threadIdx.x*2] + lds[threadIdx.x*2 + 1];
  }
}

// ---- K1: v0 = Wv@x+bv, r0 = Wr@x+br, s = mean_c x ; partial stats of r0 ----
__global__ __launch_bounds__(128) void k_proj(const float* __restrict__ x,
    const float* __restrict__ Wv, const float* __restrict__ bv,
    const float* __restrict__ Wr, const float* __restrict__ br,
    float* __restrict__ v0, float* __restrict__ r0, float* __restrict__ s,
    float* __restrict__ pr){
  __shared__ float lds[16*2];
  int tid = threadIdx.x;
  int p = blockIdx.x*128 + tid;          // < NQ
  int n = p / 800, q = p - n*800;
  int tv = q*4;
  const float* xp = x + (size_t)n*64*TV + tv;
  float av[8][4], ar[8][4];
  #pragma unroll
  for (int r = 0; r < 8; ++r)
    #pragma unroll
    for (int e = 0; e < 4; ++e){ av[r][e] = 0.f; ar[r][e] = 0.f; }
  float ss0 = 0.f, ss1 = 0.f, ss2 = 0.f, ss3 = 0.f;
  #pragma unroll 8
  for (int c = 0; c < 64; ++c){
    f4 xv = __builtin_nontemporal_load((const f4*)(xp + (size_t)c*TV));
    ss0 += xv.x; ss1 += xv.y; ss2 += xv.z; ss3 += xv.w;
    #pragma unroll
    for (int r = 0; r < 8; ++r){
      float wv = Wv[r*64 + c];           // uniform -> s_load
      float wr = Wr[r*64 + c];
      av[r][0] = fmaf(wv, xv.x, av[r][0]); av[r][1] = fmaf(wv, xv.y, av[r][1]);
      av[r][2] = fmaf(wv, xv.z, av[r][2]); av[r][3] = fmaf(wv, xv.w, av[r][3]);
      ar[r][0] = fmaf(wr, xv.x, ar[r][0]); ar[r][1] = fmaf(wr, xv.y, ar[r][1]);
      ar[r][2] = fmaf(wr, xv.z, ar[r][2]); ar[r][3] = fmaf(wr, xv.w, ar[r][3]);
    }
  }
  float4 sv; sv.x = ss0*0.015625f; sv.y = ss1*0.015625f; sv.z = ss2*0.015625f; sv.w = ss3*0.015625f;
  *(float4*)(s + (size_t)n*TV + tv) = sv;
  float* v0p = v0 + (size_t)n*8*TV + tv;
  float* r0p = r0 + (size_t)n*8*TV + tv;
  float vals[16];
  #pragma unroll
  for (int r = 0; r < 8; ++r){
    float bvr = bv[r], brr = br[r];
    float4 vv; vv.x = av[r][0]+bvr; vv.y = av[r][1]+bvr; vv.z = av[r][2]+bvr; vv.w = av[r][3]+bvr;
    *(float4*)(v0p + (size_t)r*TV) = vv;
    float r0e0 = ar[r][0]+brr, r0e1 = ar[r][1]+brr, r0e2 = ar[r][2]+brr, r0e3 = ar[r][3]+brr;
    float4 rv; rv.x = r0e0; rv.y = r0e1; rv.z = r0e2; rv.w = r0e3;
    *(float4*)(r0p + (size_t)r*TV) = rv;
    vals[r]   = r0e0 + r0e1 + r0e2 + r0e3;
    vals[8+r] = r0e0*r0e0 + r0e1*r0e1 + r0e2*r0e2 + r0e3*r0e3;
  }
  write_partials<16>(vals, pr, lds);
}

// ---- K2 (fused w2+att): att[n,r,t,v] = sum_u [sum_w tanh(Ww[w*5+u].m + bw)] * v0[n,r,t+u-2,v]
__global__ __launch_bounds__(128) void k_wat(const float* __restrict__ s,
    const float* __restrict__ Ww, const float* __restrict__ bw,
    const float* __restrict__ v0, float* __restrict__ att, float* __restrict__ patt){
  __shared__ float lds[16*2];
  int tid = threadIdx.x;
  int p = blockIdx.x*128 + tid;
  int n = p / 800, q = p - n*800;
  int tv = q*4;
  const float* sn  = s  + (size_t)n*TV;
  const float* v0n = v0 + (size_t)n*8*TV;
  float a[8][4];
  #pragma unroll
  for (int r = 0; r < 8; ++r)
    #pragma unroll
    for (int e = 0; e < 4; ++e) a[r][e] = 0.f;
  #pragma unroll
  for (int e = 0; e < 4; ++e){
    int tve = tv + e;
    int t = tve / 25;
    float m[5];
    #pragma unroll
    for (int k = 0; k < 5; ++k){
      int tt = t + k - 2;
      m[k] = (tt >= 0 && tt < 128) ? sn[tve + (k-2)*25] : 0.f;
    }
    float w2[5] = {0.f,0.f,0.f,0.f,0.f};
    #pragma unroll
    for (int w = 0; w < 5; ++w){
      #pragma unroll
      for (int u = 0; u < 5; ++u){
        int o = w*5 + u;
        float wo = bw[o];                 // uniform -> s_load
        #pragma unroll
        for (int k = 0; k < 5; ++k) wo = fmaf(Ww[o*5+k], m[k], wo);
        w2[u] += fast_tanh(wo);
      }
    }
    #pragma unroll
    for (int u = 0; u < 5; ++u){
      int tt = t + u - 2;
      if (tt >= 0 && tt < 128){
        float wu = w2[u];
        const float* vp = v0n + tve + (u-2)*25;
        #pragma unroll
        for (int r = 0; r < 8; ++r) a[r][e] = fmaf(wu, vp[(size_t)r*TV], a[r][e]);
      }
    }
  }
  float* ap = att + (size_t)n*8*TV + tv;
  float vals[16];
  #pragma unroll
  for (int r = 0; r < 8; ++r){
    float4 av4; av4.x = a[r][0]; av4.y = a[r][1]; av4.z = a[r][2]; av4.w = a[r][3];
    *(float4*)(ap + (size_t)r*TV) = av4;
    vals[r]   = a[r][0] + a[r][1] + a[r][2] + a[r][3];
    vals[8+r] = a[r][0]*a[r][0] + a[r][1]*a[r][1] + a[r][2]*a[r][2] + a[r][3]*a[r][3];
  }
  write_partials<16>(vals, patt, lds);
}

// ---- KR1: finalize BN affine coefs for att (g_bn,b_bn) and res (g_r,b_r) ----
// coef layout: a_att[0..7], c_att[8..15], a_r[16..23], c_r[24..31]
__global__ __launch_bounds__(256) void k_bncoef(const float* __restrict__ pr,
    const float* __restrict__ patt,
    const float* __restrict__ g_bn, const float* __restrict__ b_bn,
    const float* __restrict__ g_r, const float* __restrict__ b_r,
    float* __restrict__ coef){
  __shared__ float lds[8];
  int b = blockIdx.x;                 // 0..15
  bool isatt = (b >= 8);
  int r = isatt ? b - 8 : b;
  const float* ps = (isatt ? patt : pr) + r*NB;
  const float* pq = (isatt ? patt : pr) + (8+r)*NB;
  float s1 = 0.f, s2 = 0.f;
  for (int i = threadIdx.x; i < NB; i += 256){ s1 += ps[i]; s2 += pq[i]; }
  int lane = threadIdx.x & 63, wid = threadIdx.x >> 6;
  #pragma unroll
  for (int o = 32; o > 0; o >>= 1){ s1 += __shfl_down(s1, o); s2 += __shfl_down(s2, o); }
  if (lane == 0){ lds[wid] = s1; lds[4+wid] = s2; }
  __syncthreads();
  if (threadIdx.x == 0){
    float sum = lds[0]+lds[1]+lds[2]+lds[3];
    float sq  = lds[4]+lds[5]+lds[6]+lds[7];
    float mu  = sum / (float)NTV;
    float var = sq / (float)NTV - mu*mu;
    float g  = isatt ? g_bn[r] : g_r[r];
    float bb = isatt ? b_bn[r] : b_r[r];
    float a = g * rsqrtf(var + EPSF);
    float c = bb - a*mu;
    int base = isatt ? 0 : 16;
    coef[base + r] = a;
    coef[base + 8 + r] = c;
  }
}

// ---- K3: h = leaky( bn(att) + bn(r0) ) ; partial sums + upper-tri cross moments ----
__global__ __launch_bounds__(128) void k_h(const float* __restrict__ att,
    const float* __restrict__ r0, const float* __restrict__ coef,
    float* __restrict__ h, float* __restrict__ ph){
  __shared__ float lds[44*2];
  int tid = threadIdx.x;
  int p = blockIdx.x*128 + tid;
  int n = p / 800, q = p - n*800;
  int tv = q*4;
  const float* ap = att + (size_t)n*8*TV + tv;
  const float* rp = r0  + (size_t)n*8*TV + tv;
  float* hp = h + (size_t)n*8*TV + tv;
  float hv[8][4];
  #pragma unroll
  for (int r = 0; r < 8; ++r){
    float ca = coef[r], cc = coef[8+r], cr = coef[16+r], cd = coef[24+r]; // uniform
    float4 av = *(const float4*)(ap + (size_t)r*TV);
    float4 rv = *(const float4*)(rp + (size_t)r*TV);
    float z0 = ca*av.x + cc + cr*rv.x + cd;
    float z1 = ca*av.y + cc + cr*rv.y + cd;
    float z2 = ca*av.z + cc + cr*rv.z + cd;
    float z3 = ca*av.w + cc + cr*rv.w + cd;
    hv[r][0] = (z0 >= 0.f) ? z0 : 0.1f*z0;
    hv[r][1] = (z1 >= 0.f) ? z1 : 0.1f*z1;
    hv[r][2] = (z2 >= 0.f) ? z2 : 0.1f*z2;
    hv[r][3] = (z3 >= 0.f) ? z3 : 0.1f*z3;
    float4 hh; hh.x = hv[r][0]; hh.y = hv[r][1]; hh.z = hv[r][2]; hh.w = hv[r][3];
    *(float4*)(hp + (size_t)r*TV) = hh;
  }
  float vals[44];
  #pragma unroll
  for (int r = 0; r < 8; ++r) vals[r] = hv[r][0] + hv[r][1] + hv[r][2] + hv[r][3];
  int cnt = 8;
  #pragma unroll
  for (int r = 0; r < 8; ++r){
    #pragma unroll
    for (int r2 = r; r2 < 8; ++r2){
      vals[cnt++] = hv[r][0]*hv[r2][0] + hv[r][1]*hv[r2][1]
                  + hv[r][2]*hv[r2][2] + hv[r][3]*hv[r2][3];
    }
  }
  write_partials<44>(vals, ph, lds);
}

// ---- KR2+K6 merged: reduce 44 h-stats over NB partials, then fold BN into Wo',bo' ----
__global__ __launch_bounds__(256) void k_hredfold(const float* __restrict__ ph,
    const float* __restrict__ Wo, const float* __restrict__ bo,
    const float* __restrict__ g_o, const float* __restrict__ b_o,
    float* __restrict__ fold, float* __restrict__ bfold){
  __shared__ float lds[44*4];
  __shared__ float hstat[44];
  __shared__ double muh[8];
  __shared__ double exx[8][8];
  int tid = threadIdx.x, lane = tid & 63, wid = tid >> 6;   // 4 waves
  for (int j = 0; j < 44; ++j){
    float s1 = 0.f;
    for (int i = tid; i < NB; i += 256) s1 += ph[j*NB + i];
    #pragma unroll
    for (int o = 32; o > 0; o >>= 1) s1 += __shfl_down(s1, o);
    if (lane == 0) lds[j*4 + wid] = s1;
  }
  __syncthreads();
  if (tid < 44) hstat[tid] = lds[tid*4] + lds[tid*4+1] + lds[tid*4+2] + lds[tid*4+3];
  __syncthreads();
  if (tid < 8) muh[tid] = (double)hstat[tid] / (double)NTV;
  if (tid == 0){
    int cnt = 8;
    for (int r = 0; r < 8; ++r)
      for (int r2 = r; r2 < 8; ++r2){
        double e = (double)hstat[cnt++] / (double)NTV;
        exx[r][r2] = e; exx[r2][r] = e;
      }
  }
  __syncthreads();
  if (tid < 128){
    int o = tid;
    double w[8];
    for (int r = 0; r < 8; ++r) w[r] = (double)Wo[o*8+r];
    double bob = (double)bo[o];
    double mu = bob;
    for (int r = 0; r < 8; ++r) mu += w[r]*muh[r];
    double t = 0.0;
    for (int r = 0; r < 8; ++r)
      for (int r2 = 0; r2 < 8; ++r2) t += w[r]*w[r2]*exx[r][r2];
    double ey2 = t + 2.0*bob*(mu - bob) + bob*bob;
    double var = ey2 - mu*mu;
    double a = (double)g_o[o] / sqrt(var + (double)EPSF);
    for (int r = 0; r < 8; ++r) fold[o*8+r] = (float)(a * w[r]);
    bfold[o] = (float)(a * (bob - mu) + (double)b_o[o]);
  }
}

// ---- K7: out[n,o,t,v] = fold[o,:] . h[n,:,t,v] + bfold[o] ----
__global__ __launch_bounds__(128) void k_out(const float* __restrict__ h,
    const float* __restrict__ fold, const float* __restrict__ bfold,
    float* __restrict__ out){
  int tid = threadIdx.x;
  int p = blockIdx.x*128 + tid;
  int n = p / 800, q = p - n*800;
  int tv = q*4;
  const float* hp = h + (size_t)n*8*TV + tv;
  float hv[8][4];
  #pragma unroll
  for (int r = 0; r < 8; ++r){
    float4 v = *(const float4*)(hp + (size_t)r*TV);
    hv[r][0] = v.x; hv[r][1] = v.y; hv[r][2] = v.z; hv[r][3] = v.w;
  }
  float* op = out + (size_t)n*128*TV + tv;
  #pragma unroll 8
  for (int o = 0; o < 128; ++o){
    float b = bfold[o];                   // uniform -> s_load
    float y0 = b, y1 = b, y2 = b, y3 = b;
    #pragma unroll
    for (int r = 0; r < 8; ++r){
      float w = fold[o*8+r];              // uniform -> s_load
      y0 = fmaf(w, hv[r][0], y0); y1 = fmaf(w, hv[r][1], y1);
      y2 = fmaf(w, hv[r][2], y2); y3 = fmaf(w, hv[r][3], y3);
    }
    f4 yy; yy.x = y0; yy.y = y1; yy.z = y2; yy.w = y3;
    __builtin_nontemporal_store(yy, (f4*)(op + (size_t)o*TV));
  }
}

extern "C" void kernel_launch(void* const* d_in, const int* in_sizes, int n_in,
                              void* d_out, int out_size, void* d_ws, size_t ws_size,
                              hipStream_t stream){
  const float* x    = (const float*)d_in[0];
  const float* Wv   = (const float*)d_in[1];
  const float* bv   = (const float*)d_in[2];
  const float* Ww   = (const float*)d_in[3];
  const float* bw   = (const float*)d_in[4];
  const float* g_bn = (const float*)d_in[5];
  const float* b_bn = (const float*)d_in[6];
  const float* Wr   = (const float*)d_in[7];
  const float* br   = (const float*)d_in[8];
  const float* g_r  = (const float*)d_in[9];
  const float* b_r  = (const float*)d_in[10];
  const float* Wo   = (const float*)d_in[11];
  const float* bo   = (const float*)d_in[12];
  const float* g_o  = (const float*)d_in[13];
  const float* b_o  = (const float*)d_in[14];

  float* ws = (float*)d_ws;
  size_t off = 0;
  float* v0   = ws + off; off += 1638400;   // (N,8,T,V)
  float* r0   = ws + off; off += 1638400;
  float* s    = ws + off; off += 204800;    // (N,T,V)
  float* att  = ws + off; off += 1638400;
  float* hbuf = ws + off; off += 1638400;
  float* pr   = ws + off; off += 16*NB;
  float* patt = ws + off; off += 16*NB;
  float* ph   = ws + off; off += 44*NB;
  float* coef = ws + off; off += 32;
  float* fold = ws + off; off += 1024;
  float* bfold= ws + off; off += 128;

  k_proj    <<<NB, 128, 0, stream>>>(x, Wv, bv, Wr, br, v0, r0, s, pr);
  k_wat     <<<NB, 128, 0, stream>>>(s, Ww, bw, v0, att, patt);
  k_bncoef  <<<16, 256, 0, stream>>>(pr, patt, g_bn, b_bn, g_r, b_r, coef);
  k_h       <<<NB, 128, 0, stream>>>(att, r0, coef, hbuf, ph);
  k_hredfold<<<1, 256, 0, stream>>>(ph, Wo, bo, g_o, b_o, fold, bfold);
  k_out     <<<NB, 128, 0, stream>>>(hbuf, fold, bfold, (float*)d_out);
}